// Round 6
// baseline (212.727 us; speedup 1.0000x reference)
//
#include <hip/hip_runtime.h>
#include <hip/hip_bf16.h>
#include <stdint.h>

// SimpleRNN fused v4: B=16384, T=28, I=28, H=128, C=10, fp32 I/O.
// 1024 blocks x 4 waves; each wave owns 2 of 8 hidden-row tiles (jt=2w+j),
// 16 batch rows. VGPR <=128 (launch_bounds 256,4) -> 4 waves/SIMD resident.
// h exchanged per step via double-buffered LDS with raw s_barrier (lgkm-only
// drain -> x prefetch survives). bf16 hi/lo split MFMAs, fp32 accum.
// Hidden-unit permutation makes D-layout == next-step B-frag layout.

typedef __attribute__((ext_vector_type(8))) short short8;
typedef __attribute__((ext_vector_type(4))) float f32x4;
typedef __attribute__((ext_vector_type(4))) uint32_t u32x4;

union Frag { short8 s; uint32_t u[4]; u32x4 v; };

#define MFMA16(a,b,c) __builtin_amdgcn_mfma_f32_16x16x32_bf16((a),(b),(c),0,0,0)

__device__ __forceinline__ uint32_t pk2(float a, float b){
    union { __hip_bfloat162 h; uint32_t u; } cv;
    cv.h = __float22bfloat162_rn(make_float2(a,b));
    return cv.u;
}
__device__ __forceinline__ float lo16f(uint32_t u){ return __builtin_bit_cast(float, u<<16); }
__device__ __forceinline__ float hi16f(uint32_t u){ return __builtin_bit_cast(float, u & 0xffff0000u); }

__device__ __forceinline__ void cvt8(const f32x4& a, const f32x4& b, Frag& hi, Frag& lo){
    #pragma unroll
    for(int q=0;q<2;q++){
        uint32_t h = pk2(a[2*q], a[2*q+1]);
        hi.u[q] = h;
        lo.u[q] = pk2(a[2*q]-lo16f(h), a[2*q+1]-hi16f(h));
    }
    #pragma unroll
    for(int q=0;q<2;q++){
        uint32_t h = pk2(b[2*q], b[2*q+1]);
        hi.u[2+q] = h;
        lo.u[2+q] = pk2(b[2*q]-lo16f(h), b[2*q+1]-hi16f(h));
    }
}

// D slot (jt, rowidx) -> physical hidden index (layout fixed point)
__device__ __forceinline__ int piperm(int p){
    int jt = p>>4, c = p&15;
    return 32*(jt>>1) + 8*(c>>2) + 4*(jt&1) + (c&3);
}

// clamp-free tanh: 1 - 2/(e^{2x}+1). e->inf => 1, e->0 => -1.
__device__ __forceinline__ float fast_tanh(float x){
    float e = __expf(2.f*x);
    return 1.f - 2.f*__builtin_amdgcn_rcpf(e + 1.f);
}

__global__ __launch_bounds__(256,4) void rnn_v4(
    const float* __restrict__ x,   const float* __restrict__ Wih,
    const float* __restrict__ Whh, const float* __restrict__ bih,
    const float* __restrict__ bhh, const float* __restrict__ Wfc,
    const float* __restrict__ bfc, float* __restrict__ out)
{
    const int tid  = threadIdx.x;
    const int w    = tid >> 6;        // wave 0..3, owns jt = 2w+j (j=0..1), kt slice w
    const int lane = tid & 63;
    const int g = lane>>4, c = lane&15;
    const int b0 = blockIdx.x*16;
    const f32x4 zero4 = {0.f,0.f,0.f,0.f};

    // h exchange: [buf][hi/lo][kt][lane][4 u32] = 16 KB, double-buffered
    __shared__ uint32_t lds[2][2][4][64][4];

    // ---- W_hh fragments for this wave's 2 jt tiles (rows pi-permuted) ----
    Frag whh_h[2][4], whh_l[2][4];
    #pragma unroll
    for(int j=0;j<2;j++){
        const int row = piperm(16*(2*w+j) + c);
        const float* rp = Whh + row*128;
        #pragma unroll
        for(int kt=0;kt<4;kt++){
            f32x4 a = *(const f32x4*)(rp + kt*32 + 8*g);
            f32x4 b = *(const f32x4*)(rp + kt*32 + 8*g + 4);
            cvt8(a, b, whh_h[j][kt], whh_l[j][kt]);
        }
    }

    // ---- W_ih fragments (K=28 padded to 32; pad-slot WEIGHTS zeroed so the
    //      per-step x fragment needs no masking: garbage * 0 == 0) ----
    Frag wih_h[2], wih_l[2];
    {
        const int i1 = 8*g;
        const int i2 = (g<3) ? (8*g+4) : 24;
        #pragma unroll
        for(int j=0;j<2;j++){
            const int row = piperm(16*(2*w+j) + c);
            const float* rp = Wih + row*28;
            f32x4 a = *(const f32x4*)(rp + i1);
            f32x4 b = *(const f32x4*)(rp + i2);
            if (g==3) b = zero4;              // zero weights for k=28..31
            cvt8(a, b, wih_h[j], wih_l[j]);
        }
    }

    // ---- biases as MFMA C-operand ----
    f32x4 biasr[2];
    #pragma unroll
    for(int j=0;j<2;j++){
        #pragma unroll
        for(int r=0;r<4;r++){
            int q = piperm(16*(2*w+j) + 4*g + r);
            biasr[j][r] = bih[q] + bhh[q];
        }
    }

    // ---- h state fragments (full 128-wide B-layout), zero init ----
    Frag bh_h[4], bh_l[4];
    #pragma unroll
    for(int kt=0;kt<4;kt++){
        #pragma unroll
        for(int q=0;q<4;q++){ bh_h[kt].u[q]=0; bh_l[kt].u[q]=0; }
    }

    const float* xrow = x + (size_t)(b0 + c)*784;
    const int o1 = 8*g;
    const int o2 = (g<3) ? (8*g+4) : 24;      // g==3 reads dup (weights are 0)

    f32x4 xA = *(const f32x4*)(xrow + o1);
    f32x4 xB = *(const f32x4*)(xrow + o2);

    for(int t=0; t<28; ++t){
        // prefetch next timestep's x (survives raw barrier: no vmcnt drain)
        const int tn = (t<27) ? t+1 : 27;
        f32x4 xA_n = *(const f32x4*)(xrow + tn*28 + o1);
        f32x4 xB_n = *(const f32x4*)(xrow + tn*28 + o2);

        // x -> B fragment (no masking; pad weights are zero)
        Frag bx_h, bx_l;
        cvt8(xA, xB, bx_h, bx_l);

        // preact = bias + W_ih x_t + W_hh h ; 4 parallel chains (2 per jt)
        f32x4 acc[2];
        #pragma unroll
        for(int j=0;j<2;j++){
            f32x4 a1 = MFMA16(wih_h[j].s, bx_h.s, biasr[j]);
            a1 = MFMA16(wih_l[j].s, bx_h.s, a1);
            a1 = MFMA16(wih_h[j].s, bx_l.s, a1);
            a1 = MFMA16(whh_h[j][0].s, bh_h[0].s, a1);
            a1 = MFMA16(whh_l[j][0].s, bh_h[0].s, a1);
            a1 = MFMA16(whh_h[j][0].s, bh_l[0].s, a1);
            a1 = MFMA16(whh_h[j][1].s, bh_h[1].s, a1);
            a1 = MFMA16(whh_l[j][1].s, bh_h[1].s, a1);
            a1 = MFMA16(whh_h[j][1].s, bh_l[1].s, a1);
            f32x4 a2 = MFMA16(whh_h[j][2].s, bh_h[2].s, zero4);
            a2 = MFMA16(whh_l[j][2].s, bh_h[2].s, a2);
            a2 = MFMA16(whh_h[j][2].s, bh_l[2].s, a2);
            a2 = MFMA16(whh_h[j][3].s, bh_h[3].s, a2);
            a2 = MFMA16(whh_l[j][3].s, bh_h[3].s, a2);
            a2 = MFMA16(whh_h[j][3].s, bh_l[3].s, a2);
            acc[j] = a1 + a2;
        }

        // tanh + hi/lo pack; wave w produces exactly kt slice w
        Frag nh_h, nh_l;
        #pragma unroll
        for(int j=0;j<2;j++){
            float h0 = fast_tanh(acc[j][0]);
            float h1 = fast_tanh(acc[j][1]);
            float h2 = fast_tanh(acc[j][2]);
            float h3 = fast_tanh(acc[j][3]);
            const int q0 = j*2;                 // jt=2w+j -> (jt&1)=j
            uint32_t u0 = pk2(h0,h1), u1 = pk2(h2,h3);
            nh_h.u[q0]   = u0;
            nh_h.u[q0+1] = u1;
            nh_l.u[q0]   = pk2(h0-lo16f(u0), h1-hi16f(u0));
            nh_l.u[q0+1] = pk2(h2-lo16f(u1), h3-hi16f(u1));
        }

        // exchange via LDS; raw barrier drains LDS only (x loads in flight)
        const int buf = t & 1;
        *(u32x4*)(&lds[buf][0][w][lane][0]) = nh_h.v;
        *(u32x4*)(&lds[buf][1][w][lane][0]) = nh_l.v;

        asm volatile("s_waitcnt lgkmcnt(0)" ::: "memory");
        __builtin_amdgcn_s_barrier();

        #pragma unroll
        for(int kt=0;kt<4;kt++){
            bh_h[kt].v = *(const u32x4*)(&lds[buf][0][kt][lane][0]);
            bh_l[kt].v = *(const u32x4*)(&lds[buf][1][kt][lane][0]);
        }
        xA = xA_n; xB = xB_n;
    }

    // ---- FC epilogue on wave 0 (holds full final h fragments) ----
    if (w == 0){
        Frag wfc_h[4], wfc_l[4];
        const bool valid = (c < 10);
        const float* rp = Wfc + (valid ? c : 0)*128;
        #pragma unroll
        for(int kt=0;kt<4;kt++){
            f32x4 a = *(const f32x4*)(rp + kt*32 + 8*g);
            f32x4 b = *(const f32x4*)(rp + kt*32 + 8*g + 4);
            if(!valid){ a = zero4; b = zero4; }
            cvt8(a, b, wfc_h[kt], wfc_l[kt]);
        }
        f32x4 accf = {0.f,0.f,0.f,0.f};
        #pragma unroll
        for(int kt=0;kt<4;kt++){
            accf = MFMA16(wfc_h[kt].s, bh_h[kt].s, accf);
            accf = MFMA16(wfc_l[kt].s, bh_h[kt].s, accf);
            accf = MFMA16(wfc_h[kt].s, bh_l[kt].s, accf);
        }
        #pragma unroll
        for(int r=0;r<4;r++){
            int cls = 4*g + r;
            if (cls < 10){
                out[(size_t)(b0+c)*10 + cls] = accf[r] + bfc[cls];
            }
        }
    }
}

extern "C" void kernel_launch(void* const* d_in, const int* in_sizes, int n_in,
                              void* d_out, int out_size, void* d_ws, size_t ws_size,
                              hipStream_t stream)
{
    const float* x   = (const float*)d_in[0];
    const float* Wih = (const float*)d_in[1];
    const float* Whh = (const float*)d_in[2];
    const float* bih = (const float*)d_in[3];
    const float* bhh = (const float*)d_in[4];
    const float* Wfc = (const float*)d_in[5];
    const float* bfc = (const float*)d_in[6];
    float* out = (float*)d_out;

    const int nb = in_sizes[0] / 784;      // 16384
    dim3 grid(nb/16), blk(256);
    hipLaunchKernelGGL(rnn_v4, grid, blk, 0, stream,
                       x, Wih, Whh, bih, bhh, Wfc, bfc, out);
}

// Round 7
// 137.294 us; speedup vs baseline: 1.5494x; 1.5494x over previous
//
#include <hip/hip_runtime.h>
#include <hip/hip_bf16.h>
#include <stdint.h>

// SimpleRNN fused v5: B=16384, T=28, I=28, H=128, C=10, fp32 I/O.
// 1024 blocks x 8 waves; each wave owns ONE hidden-row tile (jt=w), 16 batch
// rows. Per-wave regs ~116 (incl AGPR) -> 4 waves/SIMD resident (2 blocks/CU).
// h exchanged per step via double-buffered LDS + raw s_barrier (lgkm-only
// drain; x prefetch stays in flight). W_hh uses full 3-term bf16 hi/lo split
// (recurrence precision); W_ih uses hi-only (one-shot, non-accumulating).
// All packs via v_cvt_pk_bf16_f32. Hidden-unit permutation makes MFMA
// D-layout == next-step B-frag layout (zero data movement per step).

typedef __attribute__((ext_vector_type(8))) short short8;
typedef __attribute__((ext_vector_type(4))) float f32x4;
typedef __attribute__((ext_vector_type(2))) uint32_t u32x2;
typedef __attribute__((ext_vector_type(4))) uint32_t u32x4;

union Frag { short8 s; uint32_t u[4]; u32x4 v; };

#define MFMA16(a,b,c) __builtin_amdgcn_mfma_f32_16x16x32_bf16((a),(b),(c),0,0,0)

// 1-op packed fp32->bf16x2 (RNE), lo arg -> low 16 bits
__device__ __forceinline__ uint32_t cvtpk(float lo, float hi){
    uint32_t r;
    asm("v_cvt_pk_bf16_f32 %0, %1, %2" : "=v"(r) : "v"(lo), "v"(hi));
    return r;
}
__device__ __forceinline__ float lo16f(uint32_t u){ return __builtin_bit_cast(float, u<<16); }
__device__ __forceinline__ float hi16f(uint32_t u){ return __builtin_bit_cast(float, u & 0xffff0000u); }

// 8 fp32 -> bf16 hi frag + bf16 lo (residual) frag
__device__ __forceinline__ void cvt8(const f32x4& a, const f32x4& b, Frag& hi, Frag& lo){
    hi.u[0] = cvtpk(a[0],a[1]);  hi.u[1] = cvtpk(a[2],a[3]);
    hi.u[2] = cvtpk(b[0],b[1]);  hi.u[3] = cvtpk(b[2],b[3]);
    lo.u[0] = cvtpk(a[0]-lo16f(hi.u[0]), a[1]-hi16f(hi.u[0]));
    lo.u[1] = cvtpk(a[2]-lo16f(hi.u[1]), a[3]-hi16f(hi.u[1]));
    lo.u[2] = cvtpk(b[0]-lo16f(hi.u[2]), b[1]-hi16f(hi.u[2]));
    lo.u[3] = cvtpk(b[2]-lo16f(hi.u[3]), b[3]-hi16f(hi.u[3]));
}

// D slot (jt, rowidx) -> physical hidden index (layout fixed point)
__device__ __forceinline__ int piperm(int p){
    int jt = p>>4, c = p&15;
    return 32*(jt>>1) + 8*(c>>2) + 4*(jt&1) + (c&3);
}

// clamp-free tanh: 1 - 2/(e^{2x}+1)
__device__ __forceinline__ float fast_tanh(float x){
    float e = __expf(2.f*x);
    return 1.f - 2.f*__builtin_amdgcn_rcpf(e + 1.f);
}

__global__ __launch_bounds__(512,4) void rnn_v5(
    const float* __restrict__ x,   const float* __restrict__ Wih,
    const float* __restrict__ Whh, const float* __restrict__ bih,
    const float* __restrict__ bhh, const float* __restrict__ Wfc,
    const float* __restrict__ bfc, float* __restrict__ out)
{
    const int tid  = threadIdx.x;
    const int w    = tid >> 6;        // wave 0..7, owns jt = w
    const int lane = tid & 63;
    const int g = lane>>4, c = lane&15;
    const int ks = w>>1;              // kt slice this wave produces
    const int q0 = (w&1)*2;           // u32-pair within the slice
    const int b0 = blockIdx.x*16;
    const f32x4 zero4 = {0.f,0.f,0.f,0.f};

    // h exchange: [buf][hi/lo][kt][lane][4 u32] = 16 KB, double-buffered
    __shared__ uint32_t lds[2][2][4][64][4];

    // ---- W_hh fragments for this wave's jt tile (rows pi-permuted) ----
    Frag whh_h[4], whh_l[4];
    {
        const int row = piperm(16*w + c);
        const float* rp = Whh + row*128;
        #pragma unroll
        for(int kt=0;kt<4;kt++){
            f32x4 a = *(const f32x4*)(rp + kt*32 + 8*g);
            f32x4 b = *(const f32x4*)(rp + kt*32 + 8*g + 4);
            cvt8(a, b, whh_h[kt], whh_l[kt]);
        }
    }

    // ---- W_ih fragment, hi only (K=28 padded to 32; pad weights zeroed) ----
    Frag wih_h;
    {
        const int i1 = 8*g;
        const int i2 = (g<3) ? (8*g+4) : 24;
        const int row = piperm(16*w + c);
        const float* rp = Wih + row*28;
        f32x4 a = *(const f32x4*)(rp + i1);
        f32x4 b = *(const f32x4*)(rp + i2);
        if (g==3) b = zero4;               // zero weights for k=28..31
        wih_h.u[0] = cvtpk(a[0],a[1]);  wih_h.u[1] = cvtpk(a[2],a[3]);
        wih_h.u[2] = cvtpk(b[0],b[1]);  wih_h.u[3] = cvtpk(b[2],b[3]);
    }

    // ---- bias as MFMA C-operand ----
    f32x4 biasr;
    #pragma unroll
    for(int r=0;r<4;r++){
        int q = piperm(16*w + 4*g + r);
        biasr[r] = bih[q] + bhh[q];
    }

    // ---- h state fragments (full 128-wide B-layout), zero init ----
    Frag bh_h[4], bh_l[4];
    #pragma unroll
    for(int kt=0;kt<4;kt++){
        #pragma unroll
        for(int q=0;q<4;q++){ bh_h[kt].u[q]=0; bh_l[kt].u[q]=0; }
    }

    const float* xrow = x + (size_t)(b0 + c)*784;
    const int o1 = 8*g;
    const int o2 = (g<3) ? (8*g+4) : 24;   // g==3 reads dup (weights are 0)

    f32x4 xA = *(const f32x4*)(xrow + o1);
    f32x4 xB = *(const f32x4*)(xrow + o2);

    for(int t=0; t<28; ++t){
        // prefetch next timestep's x (survives raw barrier: no vmcnt drain)
        const int tn = (t<27) ? t+1 : 27;
        f32x4 xA_n = *(const f32x4*)(xrow + tn*28 + o1);
        f32x4 xB_n = *(const f32x4*)(xrow + tn*28 + o2);

        // x -> B fragment, hi only
        Frag bx_h;
        bx_h.u[0] = cvtpk(xA[0],xA[1]);  bx_h.u[1] = cvtpk(xA[2],xA[3]);
        bx_h.u[2] = cvtpk(xB[0],xB[1]);  bx_h.u[3] = cvtpk(xB[2],xB[3]);

        // preact = bias + W_ih x_t + W_hh h ; two parallel chains
        f32x4 a1 = MFMA16(wih_h.s, bx_h.s, biasr);
        a1 = MFMA16(whh_h[0].s, bh_h[0].s, a1);
        a1 = MFMA16(whh_l[0].s, bh_h[0].s, a1);
        a1 = MFMA16(whh_h[0].s, bh_l[0].s, a1);
        a1 = MFMA16(whh_h[1].s, bh_h[1].s, a1);
        a1 = MFMA16(whh_l[1].s, bh_h[1].s, a1);
        a1 = MFMA16(whh_h[1].s, bh_l[1].s, a1);
        f32x4 a2 = MFMA16(whh_h[2].s, bh_h[2].s, zero4);
        a2 = MFMA16(whh_l[2].s, bh_h[2].s, a2);
        a2 = MFMA16(whh_h[2].s, bh_l[2].s, a2);
        a2 = MFMA16(whh_h[3].s, bh_h[3].s, a2);
        a2 = MFMA16(whh_l[3].s, bh_h[3].s, a2);
        a2 = MFMA16(whh_h[3].s, bh_l[3].s, a2);
        f32x4 acc = a1 + a2;

        // tanh + hi/lo pack: 4 values -> one u32-pair of kt slice ks
        float h0 = fast_tanh(acc[0]);
        float h1 = fast_tanh(acc[1]);
        float h2 = fast_tanh(acc[2]);
        float h3 = fast_tanh(acc[3]);
        uint32_t uh0 = cvtpk(h0,h1), uh1 = cvtpk(h2,h3);
        uint32_t ul0 = cvtpk(h0-lo16f(uh0), h1-hi16f(uh0));
        uint32_t ul1 = cvtpk(h2-lo16f(uh1), h3-hi16f(uh1));

        // exchange via LDS; raw barrier drains LDS only (x loads in flight)
        const int buf = t & 1;
        u32x2 vh = {uh0, uh1}, vl = {ul0, ul1};
        *(u32x2*)(&lds[buf][0][ks][lane][q0]) = vh;
        *(u32x2*)(&lds[buf][1][ks][lane][q0]) = vl;

        asm volatile("s_waitcnt lgkmcnt(0)" ::: "memory");
        __builtin_amdgcn_s_barrier();

        #pragma unroll
        for(int kt=0;kt<4;kt++){
            bh_h[kt].v = *(const u32x4*)(&lds[buf][0][kt][lane][0]);
            bh_l[kt].v = *(const u32x4*)(&lds[buf][1][kt][lane][0]);
        }
        xA = xA_n; xB = xB_n;
    }

    // ---- FC epilogue on wave 0 (holds full final h fragments) ----
    if (w == 0){
        Frag wfc_h[4], wfc_l[4];
        const bool valid = (c < 10);
        const float* rp = Wfc + (valid ? c : 0)*128;
        #pragma unroll
        for(int kt=0;kt<4;kt++){
            f32x4 a = *(const f32x4*)(rp + kt*32 + 8*g);
            f32x4 b = *(const f32x4*)(rp + kt*32 + 8*g + 4);
            if(!valid){ a = zero4; b = zero4; }
            cvt8(a, b, wfc_h[kt], wfc_l[kt]);
        }
        f32x4 accf = {0.f,0.f,0.f,0.f};
        #pragma unroll
        for(int kt=0;kt<4;kt++){
            accf = MFMA16(wfc_h[kt].s, bh_h[kt].s, accf);
            accf = MFMA16(wfc_l[kt].s, bh_h[kt].s, accf);
            accf = MFMA16(wfc_h[kt].s, bh_l[kt].s, accf);
        }
        #pragma unroll
        for(int r=0;r<4;r++){
            int cls = 4*g + r;
            if (cls < 10){
                out[(size_t)(b0+c)*10 + cls] = accf[r] + bfc[cls];
            }
        }
    }
}

extern "C" void kernel_launch(void* const* d_in, const int* in_sizes, int n_in,
                              void* d_out, int out_size, void* d_ws, size_t ws_size,
                              hipStream_t stream)
{
    const float* x   = (const float*)d_in[0];
    const float* Wih = (const float*)d_in[1];
    const float* Whh = (const float*)d_in[2];
    const float* bih = (const float*)d_in[3];
    const float* bhh = (const float*)d_in[4];
    const float* Wfc = (const float*)d_in[5];
    const float* bfc = (const float*)d_in[6];
    float* out = (float*)d_out;

    const int nb = in_sizes[0] / 784;      // 16384
    dim3 grid(nb/16), blk(512);
    hipLaunchKernelGGL(rnn_v5, grid, blk, 0, stream,
                       x, Wih, Whh, bih, bhh, Wfc, bfc, out);
}